// Round 10
// baseline (138.231 us; speedup 1.0000x reference)
//
#include <hip/hip_runtime.h>
#include <hip/hip_fp16.h>

// ---------------------------------------------------------------------------
// EncodedGCN, round 9: scale the bucketing passes.
// k_scatter was 41us at 7.5% occupancy (grid=256 blocks, latency-bound random
// 8B writes). NBLKA 256->1024 (4 blocks/CU), scan2 loops with carry over 1568
// block-sums, k_sort at 512 threads. Passes unchanged from round 8.
// ---------------------------------------------------------------------------

#define NBLKA  1024   // blocks in hist/scatter passes
#define BSH    7      // bucket shift -> 128 nodes/bucket
#define BNODES 128
#define MAXBK  784    // max buckets (n <= 100352)

__global__ void k_senc(const float* __restrict__ sv, const float* __restrict__ w1,
                       const float* __restrict__ b1, const float* __restrict__ w2,
                       const float* __restrict__ b2, float* __restrict__ senc) {
    __shared__ float hid[32];
    int j = threadIdx.x;
    if (j < 32) {
        float acc = b1[j];
        #pragma unroll 8
        for (int k = 0; k < 64; ++k) acc += sv[k] * w1[k * 32 + j];
        hid[j] = acc > 0.f ? acc : 0.f;
    }
    __syncthreads();
    if (j == 0) {
        float acc = b2[0];
        #pragma unroll 8
        for (int k = 0; k < 32; ++k) acc += hid[k] * w2[k];
        senc[0] = acc;
    }
}

__global__ void k_hist(const int* __restrict__ ei, int* __restrict__ hist,
                       int E, int EPB, int NBK) {
    __shared__ int lh[MAXBK];
    for (int k = threadIdx.x; k < NBK; k += blockDim.x) lh[k] = 0;
    __syncthreads();
    int b = blockIdx.x;
    int e0 = b * EPB, e1 = min(E, e0 + EPB);
    for (int e = e0 + threadIdx.x; e < e1; e += blockDim.x)
        atomicAdd(&lh[ei[E + e] >> BSH], 1);
    __syncthreads();
    for (int k = threadIdx.x; k < NBK; k += blockDim.x)
        hist[(size_t)k * NBLKA + b] = lh[k];
}

__global__ void k_scan1(int* __restrict__ data, int* __restrict__ bsum, int nflat) {
    __shared__ int s[512];
    int i = blockIdx.x * 512 + threadIdx.x;
    int v = (i < nflat) ? data[i] : 0;
    s[threadIdx.x] = v;
    __syncthreads();
    for (int off = 1; off < 512; off <<= 1) {
        int tv = (threadIdx.x >= off) ? s[threadIdx.x - off] : 0;
        __syncthreads();
        if (threadIdx.x >= off) s[threadIdx.x] += tv;
        __syncthreads();
    }
    if (i < nflat) data[i] = s[threadIdx.x] - v;
    if (threadIdx.x == 511) bsum[blockIdx.x] = s[511];
}

// single block, loops over nb block-sums in chunks of 512 with running carry
__global__ void k_scan2(int* __restrict__ bsum, int nb) {
    __shared__ int s[512];
    __shared__ int carry;
    if (threadIdx.x == 0) carry = 0;
    __syncthreads();
    for (int base = 0; base < nb; base += 512) {
        int idx = base + threadIdx.x;
        int v = (idx < nb) ? bsum[idx] : 0;
        s[threadIdx.x] = v;
        __syncthreads();
        for (int off = 1; off < 512; off <<= 1) {
            int tv = (threadIdx.x >= off) ? s[threadIdx.x - off] : 0;
            __syncthreads();
            if (threadIdx.x >= off) s[threadIdx.x] += tv;
            __syncthreads();
        }
        if (idx < nb) bsum[idx] = s[threadIdx.x] - v + carry;  // exclusive
        __syncthreads();
        if (threadIdx.x == 0) carry += s[511];
        __syncthreads();
    }
}

__global__ void k_scan3(int* __restrict__ data, const int* __restrict__ bsum, int nflat) {
    int i = blockIdx.x * 512 + threadIdx.x;
    if (i < nflat) data[i] += bsum[i >> 9];
}

__global__ void k_scatter(const int* __restrict__ ei, const float* __restrict__ ew,
                          const int* __restrict__ scanned, int2* __restrict__ ebuf,
                          int E, int EPB, int NBK) {
    __shared__ int lbase[MAXBK];
    int b = blockIdx.x;
    for (int k = threadIdx.x; k < NBK; k += blockDim.x)
        lbase[k] = scanned[(size_t)k * NBLKA + b];
    __syncthreads();
    int e0 = b * EPB, e1 = min(E, e0 + EPB);
    for (int e = e0 + threadIdx.x; e < e1; e += blockDim.x) {
        int c = ei[E + e];
        int r = ei[e];
        int k = c >> BSH;
        int pos = atomicAdd(&lbase[k], 1);
        ebuf[pos] = make_int2(r | ((c & (BNODES - 1)) << 25), __float_as_int(ew[e]));
    }
}

__global__ void k_sort(const int* __restrict__ scanned, const int2* __restrict__ ebuf,
                       int* __restrict__ row, float* __restrict__ dinv,
                       int2* __restrict__ csr, int n, int E, int NBK) {
    __shared__ int lcnt[BNODES];
    __shared__ int lofs[BNODES];
    __shared__ float lw[BNODES];
    int k = blockIdx.x;
    if (threadIdx.x < BNODES) { lcnt[threadIdx.x] = 0; lw[threadIdx.x] = 1.0f; }
    __syncthreads();
    int bs = scanned[(size_t)k * NBLKA];
    int be = (k + 1 < NBK) ? scanned[(size_t)(k + 1) * NBLKA] : E;
    for (int s = bs + threadIdx.x; s < be; s += blockDim.x) {
        int2 ent = ebuf[s];
        int cl = ((unsigned)ent.x) >> 25;
        atomicAdd(&lcnt[cl], 1);
        atomicAdd(&lw[cl], __int_as_float(ent.y));
    }
    __syncthreads();
    int v = (threadIdx.x < BNODES) ? lcnt[threadIdx.x] : 0;
    if (threadIdx.x < BNODES) lofs[threadIdx.x] = v;
    __syncthreads();
    for (int off = 1; off < BNODES; off <<= 1) {
        int tv = 0;
        if (threadIdx.x < BNODES && threadIdx.x >= off) tv = lofs[threadIdx.x - off];
        __syncthreads();
        if (threadIdx.x < BNODES && threadIdx.x >= off) lofs[threadIdx.x] += tv;
        __syncthreads();
    }
    if (threadIdx.x < BNODES) {
        int excl = lofs[threadIdx.x] - v;
        lofs[threadIdx.x] = excl;
        int i = k * BNODES + threadIdx.x;
        if (i < n) {
            row[i] = bs + excl;
            dinv[i] = rsqrtf(lw[threadIdx.x]);
        }
    }
    if (k == NBK - 1 && threadIdx.x == 0) row[n] = E;
    __syncthreads();
    for (int s = bs + threadIdx.x; s < be; s += blockDim.x) {
        int2 ent = ebuf[s];
        int cl = ((unsigned)ent.x) >> 25;
        int pos = bs + atomicAdd(&lofs[cl], 1);
        csr[pos] = make_int2(ent.x & 0x01FFFFFF, ent.y);
    }
}

__global__ void k_prep(int2* __restrict__ csr, const float* __restrict__ dinv, int E) {
    int e = blockIdx.x * blockDim.x + threadIdx.x;
    if (e >= E) return;
    int2 ent = csr[e];
    ent.y = __float_as_int(__int_as_float(ent.y) * dinv[ent.x]);
    csr[e] = ent;
}

__global__ void k_xh(const float* __restrict__ x, __half* __restrict__ xh, int n) {
    int i = blockIdx.x * blockDim.x + threadIdx.x;
    if (i >= n) return;
    const float4* xi = reinterpret_cast<const float4*>(x + (size_t)i * 8);
    float4 u = xi[0], v = xi[1];
    __half2 h0 = __floats2half2_rn(u.x, u.y);
    __half2 h1 = __floats2half2_rn(u.z, u.w);
    __half2 h2 = __floats2half2_rn(v.x, v.y);
    __half2 h3 = __floats2half2_rn(v.z, v.w);
    uint4 w;
    w.x = *reinterpret_cast<unsigned*>(&h0);
    w.y = *reinterpret_cast<unsigned*>(&h1);
    w.z = *reinterpret_cast<unsigned*>(&h2);
    w.w = *reinterpret_cast<unsigned*>(&h3);
    reinterpret_cast<uint4*>(xh + (size_t)i * 8)[0] = w;
}

// pass1, 4 lanes/node, register-lean distributed tail (round 8).
__global__ void k_pass1(const int* __restrict__ row, const int2* __restrict__ csr,
                        const float* __restrict__ dinv, const __half* __restrict__ xh,
                        const float* __restrict__ senc,
                        const float* __restrict__ W1, const float* __restrict__ b1,
                        const float* __restrict__ W2, __half* __restrict__ th, int n) {
    __shared__ float sW1[288];
    __shared__ float sb1[32];
    __shared__ float sW2[32 * 17];
    for (int j = threadIdx.x; j < 288; j += blockDim.x) sW1[j] = W1[j];
    for (int j = threadIdx.x; j < 512; j += blockDim.x) sW2[(j >> 4) * 17 + (j & 15)] = W2[j];
    if (threadIdx.x < 32) sb1[threadIdx.x] = b1[threadIdx.x];
    __syncthreads();
    int g = blockIdx.x * blockDim.x + threadIdx.x;
    int i = g >> 2;
    int quad = g & 3;
    if (i >= n) return;
    float di = dinv[i];
    float a[8];
    float sw;
    if (quad == 0) {
        const uint4* xp = reinterpret_cast<const uint4*>(xh + (size_t)i * 8);
        uint4 w = xp[0];
        const __half2* hh = reinterpret_cast<const __half2*>(&w);
        #pragma unroll
        for (int q = 0; q < 4; ++q) {
            float2 f = __half22float2(hh[q]);
            a[2 * q] = di * f.x; a[2 * q + 1] = di * f.y;
        }
        sw = di;
    } else {
        #pragma unroll
        for (int q = 0; q < 8; ++q) a[q] = 0.f;
        sw = 0.f;
    }
    int s0 = row[i], s1 = row[i + 1];
    for (int s = s0 + quad; s < s1; s += 4) {
        int2 ent = csr[s];
        float wpre = __int_as_float(ent.y);
        const uint4* xp = reinterpret_cast<const uint4*>(xh + (size_t)ent.x * 8);
        uint4 w = xp[0];
        const __half2* hh = reinterpret_cast<const __half2*>(&w);
        #pragma unroll
        for (int q = 0; q < 4; ++q) {
            float2 f = __half22float2(hh[q]);
            a[2 * q] += wpre * f.x; a[2 * q + 1] += wpre * f.y;
        }
        sw += wpre;
    }
    #pragma unroll
    for (int q = 0; q < 8; ++q) a[q] += __shfl_xor(a[q], 1);
    sw += __shfl_xor(sw, 1);
    #pragma unroll
    for (int q = 0; q < 8; ++q) a[q] += __shfl_xor(a[q], 2);
    sw += __shfl_xor(sw, 2);
    float a8 = di * sw * senc[0];
    float af[8];
    #pragma unroll
    for (int q = 0; q < 8; ++q) af[q] = di * a[q];
    float h[8];
    #pragma unroll
    for (int jj = 0; jj < 8; ++jj) {
        int j = quad * 8 + jj;
        float acc = sb1[j] + a8 * sW1[8 * 32 + j];
        #pragma unroll
        for (int f = 0; f < 8; ++f) acc += af[f] * sW1[f * 32 + j];
        h[jj] = acc > 0.f ? acc : 0.01f * acc;
    }
    float p[16];
    #pragma unroll
    for (int o = 0; o < 16; ++o) p[o] = 0.f;
    #pragma unroll
    for (int jj = 0; jj < 8; ++jj) {
        int j = quad * 8 + jj;
        #pragma unroll
        for (int o = 0; o < 16; ++o) p[o] += h[jj] * sW2[j * 17 + o];
    }
    #pragma unroll
    for (int o = 0; o < 16; ++o) p[o] += __shfl_xor(p[o], 1);
    #pragma unroll
    for (int o = 0; o < 16; ++o) p[o] += __shfl_xor(p[o], 2);
    int o0 = quad * 4;
    __half2 hv0 = __floats2half2_rn(p[o0 + 0], p[o0 + 1]);
    __half2 hv1 = __floats2half2_rn(p[o0 + 2], p[o0 + 3]);
    uint2 st;
    st.x = *reinterpret_cast<unsigned*>(&hv0);
    st.y = *reinterpret_cast<unsigned*>(&hv1);
    reinterpret_cast<uint2*>(th + (size_t)i * 16 + o0)[0] = st;
}

// pass2, 4 lanes/node (unchanged)
__global__ void k_pass2(const int* __restrict__ row, const int2* __restrict__ csr,
                        const float* __restrict__ dinv, const __half* __restrict__ th,
                        const float* __restrict__ b2, const float* __restrict__ fw,
                        const float* __restrict__ fb, float* __restrict__ out, int n) {
    __shared__ float sb2[16];
    __shared__ float sfw[16];
    if (threadIdx.x < 16) { sb2[threadIdx.x] = b2[threadIdx.x]; sfw[threadIdx.x] = fw[threadIdx.x]; }
    __syncthreads();
    int g = blockIdx.x * blockDim.x + threadIdx.x;
    int i = g >> 2;
    int quad = g & 3;
    if (i >= n) return;
    float di = dinv[i];
    float acc[16];
    if (quad == 0) {
        const uint4* tp = reinterpret_cast<const uint4*>(th + (size_t)i * 16);
        uint4 w0 = tp[0], w1 = tp[1];
        const __half2* hh0 = reinterpret_cast<const __half2*>(&w0);
        const __half2* hh1 = reinterpret_cast<const __half2*>(&w1);
        #pragma unroll
        for (int q = 0; q < 4; ++q) {
            float2 f0 = __half22float2(hh0[q]);
            float2 f1 = __half22float2(hh1[q]);
            acc[2 * q + 0] = di * f0.x; acc[2 * q + 1] = di * f0.y;
            acc[8 + 2 * q + 0] = di * f1.x; acc[8 + 2 * q + 1] = di * f1.y;
        }
    } else {
        #pragma unroll
        for (int q = 0; q < 16; ++q) acc[q] = 0.f;
    }
    int s0 = row[i], s1 = row[i + 1];
    for (int s = s0 + quad; s < s1; s += 4) {
        int2 ent = csr[s];
        float wpre = __int_as_float(ent.y);
        const uint4* tp = reinterpret_cast<const uint4*>(th + (size_t)ent.x * 16);
        uint4 w0 = tp[0], w1 = tp[1];
        const __half2* hh0 = reinterpret_cast<const __half2*>(&w0);
        const __half2* hh1 = reinterpret_cast<const __half2*>(&w1);
        #pragma unroll
        for (int q = 0; q < 4; ++q) {
            float2 f0 = __half22float2(hh0[q]);
            float2 f1 = __half22float2(hh1[q]);
            acc[2 * q + 0] += wpre * f0.x; acc[2 * q + 1] += wpre * f0.y;
            acc[8 + 2 * q + 0] += wpre * f1.x; acc[8 + 2 * q + 1] += wpre * f1.y;
        }
    }
    #pragma unroll
    for (int q = 0; q < 16; ++q) acc[q] += __shfl_xor(acc[q], 1);
    #pragma unroll
    for (int q = 0; q < 16; ++q) acc[q] += __shfl_xor(acc[q], 2);
    if (quad) return;
    float o = fb[0];
    #pragma unroll
    for (int q = 0; q < 16; ++q) {
        float v = di * acc[q] + sb2[q];
        v = v > 0.f ? v : 0.01f * v;
        o += v * sfw[q];
    }
    out[i] = o;
}

extern "C" void kernel_launch(void* const* d_in, const int* in_sizes, int n_in,
                              void* d_out, int out_size, void* d_ws, size_t ws_size,
                              hipStream_t stream) {
    const float* x      = (const float*)d_in[0];
    const int*   ei     = (const int*)d_in[1];
    const float* ew     = (const float*)d_in[2];
    const float* sv     = (const float*)d_in[3];
    const float* sfc1w  = (const float*)d_in[4];
    const float* sfc1b  = (const float*)d_in[5];
    const float* sfc2w  = (const float*)d_in[6];
    const float* sfc2b  = (const float*)d_in[7];
    const float* conv1w = (const float*)d_in[8];
    const float* conv1b = (const float*)d_in[9];
    const float* conv2w = (const float*)d_in[10];
    const float* conv2b = (const float*)d_in[11];
    const float* fc1w   = (const float*)d_in[12];
    const float* fc1b   = (const float*)d_in[13];

    const int n = in_sizes[0] / 8;
    const int E = in_sizes[2];

    const int NBK   = (n + BNODES - 1) >> BSH;
    const int nflat = NBK * NBLKA;
    const int EPB   = (E + NBLKA - 1) / NBLKA;
    const int nb1   = (nflat + 511) / 512;

    size_t off = 0;
    auto alloc = [&](size_t words) { size_t o = off; off += (words + 3) & ~(size_t)3; return o; };
    float*  base = (float*)d_ws;
    float*  senc = base + alloc(4);
    float*  dinv = base + alloc(n);
    int*    rowp = (int*)(base + alloc(n + 1));
    int*    hist = (int*)(base + alloc(nflat));
    int*    bsum = (int*)(base + alloc(2048));
    int2*   ebuf = (int2*)(base + alloc((size_t)2 * E));
    int2*   csr  = (int2*)(base + alloc((size_t)2 * E));
    __half* xh   = (__half*)(base + alloc((size_t)4 * n));
    __half* th   = (__half*)(base + alloc((size_t)8 * n));

    const int BT = 256;
    const int gN = (n + BT - 1) / BT;
    const int gE = (E + BT - 1) / BT;
    const int g4 = ((size_t)4 * n + BT - 1) / BT;

    k_senc<<<1, 64, 0, stream>>>(sv, sfc1w, sfc1b, sfc2w, sfc2b, senc);
    k_xh<<<gN, BT, 0, stream>>>(x, xh, n);
    k_hist<<<NBLKA, 256, 0, stream>>>(ei, hist, E, EPB, NBK);
    k_scan1<<<nb1, 512, 0, stream>>>(hist, bsum, nflat);
    k_scan2<<<1, 512, 0, stream>>>(bsum, nb1);
    k_scan3<<<nb1, 512, 0, stream>>>(hist, bsum, nflat);
    k_scatter<<<NBLKA, 256, 0, stream>>>(ei, ew, hist, ebuf, E, EPB, NBK);
    k_sort<<<NBK, 512, 0, stream>>>(hist, ebuf, rowp, dinv, csr, n, E, NBK);
    k_prep<<<gE, BT, 0, stream>>>(csr, dinv, E);
    k_pass1<<<g4, BT, 0, stream>>>(rowp, csr, dinv, xh, senc,
                                   conv1w, conv1b, conv2w, th, n);
    k_pass2<<<g4, BT, 0, stream>>>(rowp, csr, dinv, th,
                                   conv2b, fc1w, fc1b, (float*)d_out, n);
}

// Round 11
// 116.397 us; speedup vs baseline: 1.1876x; 1.1876x over previous
//
#include <hip/hip_runtime.h>
#include <hip/hip_fp16.h>

// ---------------------------------------------------------------------------
// EncodedGCN, round 10: post-mortem of r9 — more scatter parallelism must come
// from threads/block, not blocks (hist/scan cost scales with NBLKA).
// NBLKA back to 256; k_hist & k_scatter at 1024 threads/block (16 waves/CU).
// Everything else = round 8 (126us baseline).
// ---------------------------------------------------------------------------

#define NBLKA  256    // histogram columns == hist/scatter grid
#define BSH    7      // bucket shift -> 128 nodes/bucket
#define BNODES 128
#define MAXBK  784    // max buckets (n <= 100352)

__global__ void k_senc(const float* __restrict__ sv, const float* __restrict__ w1,
                       const float* __restrict__ b1, const float* __restrict__ w2,
                       const float* __restrict__ b2, float* __restrict__ senc) {
    __shared__ float hid[32];
    int j = threadIdx.x;
    if (j < 32) {
        float acc = b1[j];
        #pragma unroll 8
        for (int k = 0; k < 64; ++k) acc += sv[k] * w1[k * 32 + j];
        hid[j] = acc > 0.f ? acc : 0.f;
    }
    __syncthreads();
    if (j == 0) {
        float acc = b2[0];
        #pragma unroll 8
        for (int k = 0; k < 32; ++k) acc += hid[k] * w2[k];
        senc[0] = acc;
    }
}

// 1024 threads/block, 256 blocks
__global__ void k_hist(const int* __restrict__ ei, int* __restrict__ hist,
                       int E, int EPB, int NBK) {
    __shared__ int lh[MAXBK];
    for (int k = threadIdx.x; k < NBK; k += blockDim.x) lh[k] = 0;
    __syncthreads();
    int b = blockIdx.x;
    int e0 = b * EPB, e1 = min(E, e0 + EPB);
    for (int e = e0 + threadIdx.x; e < e1; e += blockDim.x)
        atomicAdd(&lh[ei[E + e] >> BSH], 1);
    __syncthreads();
    for (int k = threadIdx.x; k < NBK; k += blockDim.x)
        hist[(size_t)k * NBLKA + b] = lh[k];
}

__global__ void k_scan1(int* __restrict__ data, int* __restrict__ bsum, int nflat) {
    __shared__ int s[512];
    int i = blockIdx.x * 512 + threadIdx.x;
    int v = (i < nflat) ? data[i] : 0;
    s[threadIdx.x] = v;
    __syncthreads();
    for (int off = 1; off < 512; off <<= 1) {
        int tv = (threadIdx.x >= off) ? s[threadIdx.x - off] : 0;
        __syncthreads();
        if (threadIdx.x >= off) s[threadIdx.x] += tv;
        __syncthreads();
    }
    if (i < nflat) data[i] = s[threadIdx.x] - v;
    if (threadIdx.x == 511) bsum[blockIdx.x] = s[511];
}

// single block, loops with running carry (handles any nb)
__global__ void k_scan2(int* __restrict__ bsum, int nb) {
    __shared__ int s[512];
    __shared__ int carry;
    if (threadIdx.x == 0) carry = 0;
    __syncthreads();
    for (int base = 0; base < nb; base += 512) {
        int idx = base + threadIdx.x;
        int v = (idx < nb) ? bsum[idx] : 0;
        s[threadIdx.x] = v;
        __syncthreads();
        for (int off = 1; off < 512; off <<= 1) {
            int tv = (threadIdx.x >= off) ? s[threadIdx.x - off] : 0;
            __syncthreads();
            if (threadIdx.x >= off) s[threadIdx.x] += tv;
            __syncthreads();
        }
        if (idx < nb) bsum[idx] = s[threadIdx.x] - v + carry;
        __syncthreads();
        if (threadIdx.x == 0) carry += s[511];
        __syncthreads();
    }
}

__global__ void k_scan3(int* __restrict__ data, const int* __restrict__ bsum, int nflat) {
    int i = blockIdx.x * 512 + threadIdx.x;
    if (i < nflat) data[i] += bsum[i >> 9];
}

// 1024 threads/block, 256 blocks
__global__ void k_scatter(const int* __restrict__ ei, const float* __restrict__ ew,
                          const int* __restrict__ scanned, int2* __restrict__ ebuf,
                          int E, int EPB, int NBK) {
    __shared__ int lbase[MAXBK];
    int b = blockIdx.x;
    for (int k = threadIdx.x; k < NBK; k += blockDim.x)
        lbase[k] = scanned[(size_t)k * NBLKA + b];
    __syncthreads();
    int e0 = b * EPB, e1 = min(E, e0 + EPB);
    for (int e = e0 + threadIdx.x; e < e1; e += blockDim.x) {
        int c = ei[E + e];
        int r = ei[e];
        int k = c >> BSH;
        int pos = atomicAdd(&lbase[k], 1);
        ebuf[pos] = make_int2(r | ((c & (BNODES - 1)) << 25), __float_as_int(ew[e]));
    }
}

__global__ void k_sort(const int* __restrict__ scanned, const int2* __restrict__ ebuf,
                       int* __restrict__ row, float* __restrict__ dinv,
                       int2* __restrict__ csr, int n, int E, int NBK) {
    __shared__ int lcnt[BNODES];
    __shared__ int lofs[BNODES];
    __shared__ float lw[BNODES];
    int k = blockIdx.x;
    if (threadIdx.x < BNODES) { lcnt[threadIdx.x] = 0; lw[threadIdx.x] = 1.0f; }
    __syncthreads();
    int bs = scanned[(size_t)k * NBLKA];
    int be = (k + 1 < NBK) ? scanned[(size_t)(k + 1) * NBLKA] : E;
    for (int s = bs + threadIdx.x; s < be; s += blockDim.x) {
        int2 ent = ebuf[s];
        int cl = ((unsigned)ent.x) >> 25;
        atomicAdd(&lcnt[cl], 1);
        atomicAdd(&lw[cl], __int_as_float(ent.y));
    }
    __syncthreads();
    int v = (threadIdx.x < BNODES) ? lcnt[threadIdx.x] : 0;
    if (threadIdx.x < BNODES) lofs[threadIdx.x] = v;
    __syncthreads();
    for (int off = 1; off < BNODES; off <<= 1) {
        int tv = 0;
        if (threadIdx.x < BNODES && threadIdx.x >= off) tv = lofs[threadIdx.x - off];
        __syncthreads();
        if (threadIdx.x < BNODES && threadIdx.x >= off) lofs[threadIdx.x] += tv;
        __syncthreads();
    }
    if (threadIdx.x < BNODES) {
        int excl = lofs[threadIdx.x] - v;
        lofs[threadIdx.x] = excl;
        int i = k * BNODES + threadIdx.x;
        if (i < n) {
            row[i] = bs + excl;
            dinv[i] = rsqrtf(lw[threadIdx.x]);
        }
    }
    if (k == NBK - 1 && threadIdx.x == 0) row[n] = E;
    __syncthreads();
    for (int s = bs + threadIdx.x; s < be; s += blockDim.x) {
        int2 ent = ebuf[s];
        int cl = ((unsigned)ent.x) >> 25;
        int pos = bs + atomicAdd(&lofs[cl], 1);
        csr[pos] = make_int2(ent.x & 0x01FFFFFF, ent.y);
    }
}

__global__ void k_prep(int2* __restrict__ csr, const float* __restrict__ dinv, int E) {
    int e = blockIdx.x * blockDim.x + threadIdx.x;
    if (e >= E) return;
    int2 ent = csr[e];
    ent.y = __float_as_int(__int_as_float(ent.y) * dinv[ent.x]);
    csr[e] = ent;
}

__global__ void k_xh(const float* __restrict__ x, __half* __restrict__ xh, int n) {
    int i = blockIdx.x * blockDim.x + threadIdx.x;
    if (i >= n) return;
    const float4* xi = reinterpret_cast<const float4*>(x + (size_t)i * 8);
    float4 u = xi[0], v = xi[1];
    __half2 h0 = __floats2half2_rn(u.x, u.y);
    __half2 h1 = __floats2half2_rn(u.z, u.w);
    __half2 h2 = __floats2half2_rn(v.x, v.y);
    __half2 h3 = __floats2half2_rn(v.z, v.w);
    uint4 w;
    w.x = *reinterpret_cast<unsigned*>(&h0);
    w.y = *reinterpret_cast<unsigned*>(&h1);
    w.z = *reinterpret_cast<unsigned*>(&h2);
    w.w = *reinterpret_cast<unsigned*>(&h3);
    reinterpret_cast<uint4*>(xh + (size_t)i * 8)[0] = w;
}

// pass1, 4 lanes/node, register-lean distributed tail (round 8).
__global__ void k_pass1(const int* __restrict__ row, const int2* __restrict__ csr,
                        const float* __restrict__ dinv, const __half* __restrict__ xh,
                        const float* __restrict__ senc,
                        const float* __restrict__ W1, const float* __restrict__ b1,
                        const float* __restrict__ W2, __half* __restrict__ th, int n) {
    __shared__ float sW1[288];
    __shared__ float sb1[32];
    __shared__ float sW2[32 * 17];
    for (int j = threadIdx.x; j < 288; j += blockDim.x) sW1[j] = W1[j];
    for (int j = threadIdx.x; j < 512; j += blockDim.x) sW2[(j >> 4) * 17 + (j & 15)] = W2[j];
    if (threadIdx.x < 32) sb1[threadIdx.x] = b1[threadIdx.x];
    __syncthreads();
    int g = blockIdx.x * blockDim.x + threadIdx.x;
    int i = g >> 2;
    int quad = g & 3;
    if (i >= n) return;
    float di = dinv[i];
    float a[8];
    float sw;
    if (quad == 0) {
        const uint4* xp = reinterpret_cast<const uint4*>(xh + (size_t)i * 8);
        uint4 w = xp[0];
        const __half2* hh = reinterpret_cast<const __half2*>(&w);
        #pragma unroll
        for (int q = 0; q < 4; ++q) {
            float2 f = __half22float2(hh[q]);
            a[2 * q] = di * f.x; a[2 * q + 1] = di * f.y;
        }
        sw = di;
    } else {
        #pragma unroll
        for (int q = 0; q < 8; ++q) a[q] = 0.f;
        sw = 0.f;
    }
    int s0 = row[i], s1 = row[i + 1];
    for (int s = s0 + quad; s < s1; s += 4) {
        int2 ent = csr[s];
        float wpre = __int_as_float(ent.y);
        const uint4* xp = reinterpret_cast<const uint4*>(xh + (size_t)ent.x * 8);
        uint4 w = xp[0];
        const __half2* hh = reinterpret_cast<const __half2*>(&w);
        #pragma unroll
        for (int q = 0; q < 4; ++q) {
            float2 f = __half22float2(hh[q]);
            a[2 * q] += wpre * f.x; a[2 * q + 1] += wpre * f.y;
        }
        sw += wpre;
    }
    #pragma unroll
    for (int q = 0; q < 8; ++q) a[q] += __shfl_xor(a[q], 1);
    sw += __shfl_xor(sw, 1);
    #pragma unroll
    for (int q = 0; q < 8; ++q) a[q] += __shfl_xor(a[q], 2);
    sw += __shfl_xor(sw, 2);
    float a8 = di * sw * senc[0];
    float af[8];
    #pragma unroll
    for (int q = 0; q < 8; ++q) af[q] = di * a[q];
    float h[8];
    #pragma unroll
    for (int jj = 0; jj < 8; ++jj) {
        int j = quad * 8 + jj;
        float acc = sb1[j] + a8 * sW1[8 * 32 + j];
        #pragma unroll
        for (int f = 0; f < 8; ++f) acc += af[f] * sW1[f * 32 + j];
        h[jj] = acc > 0.f ? acc : 0.01f * acc;
    }
    float p[16];
    #pragma unroll
    for (int o = 0; o < 16; ++o) p[o] = 0.f;
    #pragma unroll
    for (int jj = 0; jj < 8; ++jj) {
        int j = quad * 8 + jj;
        #pragma unroll
        for (int o = 0; o < 16; ++o) p[o] += h[jj] * sW2[j * 17 + o];
    }
    #pragma unroll
    for (int o = 0; o < 16; ++o) p[o] += __shfl_xor(p[o], 1);
    #pragma unroll
    for (int o = 0; o < 16; ++o) p[o] += __shfl_xor(p[o], 2);
    int o0 = quad * 4;
    __half2 hv0 = __floats2half2_rn(p[o0 + 0], p[o0 + 1]);
    __half2 hv1 = __floats2half2_rn(p[o0 + 2], p[o0 + 3]);
    uint2 st;
    st.x = *reinterpret_cast<unsigned*>(&hv0);
    st.y = *reinterpret_cast<unsigned*>(&hv1);
    reinterpret_cast<uint2*>(th + (size_t)i * 16 + o0)[0] = st;
}

// pass2, 4 lanes/node
__global__ void k_pass2(const int* __restrict__ row, const int2* __restrict__ csr,
                        const float* __restrict__ dinv, const __half* __restrict__ th,
                        const float* __restrict__ b2, const float* __restrict__ fw,
                        const float* __restrict__ fb, float* __restrict__ out, int n) {
    __shared__ float sb2[16];
    __shared__ float sfw[16];
    if (threadIdx.x < 16) { sb2[threadIdx.x] = b2[threadIdx.x]; sfw[threadIdx.x] = fw[threadIdx.x]; }
    __syncthreads();
    int g = blockIdx.x * blockDim.x + threadIdx.x;
    int i = g >> 2;
    int quad = g & 3;
    if (i >= n) return;
    float di = dinv[i];
    float acc[16];
    if (quad == 0) {
        const uint4* tp = reinterpret_cast<const uint4*>(th + (size_t)i * 16);
        uint4 w0 = tp[0], w1 = tp[1];
        const __half2* hh0 = reinterpret_cast<const __half2*>(&w0);
        const __half2* hh1 = reinterpret_cast<const __half2*>(&w1);
        #pragma unroll
        for (int q = 0; q < 4; ++q) {
            float2 f0 = __half22float2(hh0[q]);
            float2 f1 = __half22float2(hh1[q]);
            acc[2 * q + 0] = di * f0.x; acc[2 * q + 1] = di * f0.y;
            acc[8 + 2 * q + 0] = di * f1.x; acc[8 + 2 * q + 1] = di * f1.y;
        }
    } else {
        #pragma unroll
        for (int q = 0; q < 16; ++q) acc[q] = 0.f;
    }
    int s0 = row[i], s1 = row[i + 1];
    for (int s = s0 + quad; s < s1; s += 4) {
        int2 ent = csr[s];
        float wpre = __int_as_float(ent.y);
        const uint4* tp = reinterpret_cast<const uint4*>(th + (size_t)ent.x * 16);
        uint4 w0 = tp[0], w1 = tp[1];
        const __half2* hh0 = reinterpret_cast<const __half2*>(&w0);
        const __half2* hh1 = reinterpret_cast<const __half2*>(&w1);
        #pragma unroll
        for (int q = 0; q < 4; ++q) {
            float2 f0 = __half22float2(hh0[q]);
            float2 f1 = __half22float2(hh1[q]);
            acc[2 * q + 0] += wpre * f0.x; acc[2 * q + 1] += wpre * f0.y;
            acc[8 + 2 * q + 0] += wpre * f1.x; acc[8 + 2 * q + 1] += wpre * f1.y;
        }
    }
    #pragma unroll
    for (int q = 0; q < 16; ++q) acc[q] += __shfl_xor(acc[q], 1);
    #pragma unroll
    for (int q = 0; q < 16; ++q) acc[q] += __shfl_xor(acc[q], 2);
    if (quad) return;
    float o = fb[0];
    #pragma unroll
    for (int q = 0; q < 16; ++q) {
        float v = di * acc[q] + sb2[q];
        v = v > 0.f ? v : 0.01f * v;
        o += v * sfw[q];
    }
    out[i] = o;
}

extern "C" void kernel_launch(void* const* d_in, const int* in_sizes, int n_in,
                              void* d_out, int out_size, void* d_ws, size_t ws_size,
                              hipStream_t stream) {
    const float* x      = (const float*)d_in[0];
    const int*   ei     = (const int*)d_in[1];
    const float* ew     = (const float*)d_in[2];
    const float* sv     = (const float*)d_in[3];
    const float* sfc1w  = (const float*)d_in[4];
    const float* sfc1b  = (const float*)d_in[5];
    const float* sfc2w  = (const float*)d_in[6];
    const float* sfc2b  = (const float*)d_in[7];
    const float* conv1w = (const float*)d_in[8];
    const float* conv1b = (const float*)d_in[9];
    const float* conv2w = (const float*)d_in[10];
    const float* conv2b = (const float*)d_in[11];
    const float* fc1w   = (const float*)d_in[12];
    const float* fc1b   = (const float*)d_in[13];

    const int n = in_sizes[0] / 8;
    const int E = in_sizes[2];

    const int NBK   = (n + BNODES - 1) >> BSH;
    const int nflat = NBK * NBLKA;
    const int EPB   = (E + NBLKA - 1) / NBLKA;
    const int nb1   = (nflat + 511) / 512;

    size_t off = 0;
    auto alloc = [&](size_t words) { size_t o = off; off += (words + 3) & ~(size_t)3; return o; };
    float*  base = (float*)d_ws;
    float*  senc = base + alloc(4);
    float*  dinv = base + alloc(n);
    int*    rowp = (int*)(base + alloc(n + 1));
    int*    hist = (int*)(base + alloc(nflat));
    int*    bsum = (int*)(base + alloc(512));
    int2*   ebuf = (int2*)(base + alloc((size_t)2 * E));
    int2*   csr  = (int2*)(base + alloc((size_t)2 * E));
    __half* xh   = (__half*)(base + alloc((size_t)4 * n));
    __half* th   = (__half*)(base + alloc((size_t)8 * n));

    const int BT = 256;
    const int gN = (n + BT - 1) / BT;
    const int gE = (E + BT - 1) / BT;
    const int g4 = ((size_t)4 * n + BT - 1) / BT;

    k_senc<<<1, 64, 0, stream>>>(sv, sfc1w, sfc1b, sfc2w, sfc2b, senc);
    k_xh<<<gN, BT, 0, stream>>>(x, xh, n);
    k_hist<<<NBLKA, 1024, 0, stream>>>(ei, hist, E, EPB, NBK);
    k_scan1<<<nb1, 512, 0, stream>>>(hist, bsum, nflat);
    k_scan2<<<1, 512, 0, stream>>>(bsum, nb1);
    k_scan3<<<nb1, 512, 0, stream>>>(hist, bsum, nflat);
    k_scatter<<<NBLKA, 1024, 0, stream>>>(ei, ew, hist, ebuf, E, EPB, NBK);
    k_sort<<<NBK, 512, 0, stream>>>(hist, ebuf, rowp, dinv, csr, n, E, NBK);
    k_prep<<<gE, BT, 0, stream>>>(csr, dinv, E);
    k_pass1<<<g4, BT, 0, stream>>>(rowp, csr, dinv, xh, senc,
                                   conv1w, conv1b, conv2w, th, n);
    k_pass2<<<g4, BT, 0, stream>>>(rowp, csr, dinv, th,
                                   conv2b, fc1w, fc1b, (float*)d_out, n);
}

// Round 12
// 105.254 us; speedup vs baseline: 1.3133x; 1.1059x over previous
//
#include <hip/hip_runtime.h>
#include <hip/hip_fp16.h>

// ---------------------------------------------------------------------------
// EncodedGCN, round 11: compact 4B CSR entries + kernel-count reduction.
//  - csr entry = (fp16_nosign(w) << 17) | src   (src < 2^17; w > 0)
//    halves sort-write / prep-rw / pass-stream traffic (~32MB total)
//  - scan3 folded into scatter & sort (base = hist[] + bsum[idx>>9])
//  - senc folded into k_xh as an extra block
// Build config = round 10 (NBLKA=256 cols, 1024-thread hist/scatter).
// ---------------------------------------------------------------------------

#define NBLKA  256
#define BSH    7
#define BNODES 128
#define MAXBK  784

__device__ inline unsigned enc_w(float w) {
    return ((unsigned)__half_as_ushort(__float2half_rn(w)) & 0x7FFFu) << 17;
}
__device__ inline float dec_w(unsigned e) {
    return __half2float(__ushort_as_half((unsigned short)((e >> 17) & 0x7FFFu)));
}

// xh conversion; last block computes the s-encoder scalar instead.
__global__ void k_xh(const float* __restrict__ x, __half* __restrict__ xh, int n,
                     const float* __restrict__ sv, const float* __restrict__ w1,
                     const float* __restrict__ b1, const float* __restrict__ w2,
                     const float* __restrict__ b2, float* __restrict__ senc) {
    if (blockIdx.x == gridDim.x - 1) {
        __shared__ float hid[32];
        int j = threadIdx.x;
        if (j < 32) {
            float acc = b1[j];
            #pragma unroll 8
            for (int k = 0; k < 64; ++k) acc += sv[k] * w1[k * 32 + j];
            hid[j] = acc > 0.f ? acc : 0.f;
        }
        __syncthreads();
        if (j == 0) {
            float acc = b2[0];
            #pragma unroll 8
            for (int k = 0; k < 32; ++k) acc += hid[k] * w2[k];
            senc[0] = acc;
        }
        return;
    }
    int i = blockIdx.x * blockDim.x + threadIdx.x;
    if (i >= n) return;
    const float4* xi = reinterpret_cast<const float4*>(x + (size_t)i * 8);
    float4 u = xi[0], v = xi[1];
    __half2 h0 = __floats2half2_rn(u.x, u.y);
    __half2 h1 = __floats2half2_rn(u.z, u.w);
    __half2 h2 = __floats2half2_rn(v.x, v.y);
    __half2 h3 = __floats2half2_rn(v.z, v.w);
    uint4 w;
    w.x = *reinterpret_cast<unsigned*>(&h0);
    w.y = *reinterpret_cast<unsigned*>(&h1);
    w.z = *reinterpret_cast<unsigned*>(&h2);
    w.w = *reinterpret_cast<unsigned*>(&h3);
    reinterpret_cast<uint4*>(xh + (size_t)i * 8)[0] = w;
}

// 1024 threads/block, 256 blocks
__global__ void k_hist(const int* __restrict__ ei, int* __restrict__ hist,
                       int E, int EPB, int NBK) {
    __shared__ int lh[MAXBK];
    for (int k = threadIdx.x; k < NBK; k += blockDim.x) lh[k] = 0;
    __syncthreads();
    int b = blockIdx.x;
    int e0 = b * EPB, e1 = min(E, e0 + EPB);
    for (int e = e0 + threadIdx.x; e < e1; e += blockDim.x)
        atomicAdd(&lh[ei[E + e] >> BSH], 1);
    __syncthreads();
    for (int k = threadIdx.x; k < NBK; k += blockDim.x)
        hist[(size_t)k * NBLKA + b] = lh[k];
}

__global__ void k_scan1(int* __restrict__ data, int* __restrict__ bsum, int nflat) {
    __shared__ int s[512];
    int i = blockIdx.x * 512 + threadIdx.x;
    int v = (i < nflat) ? data[i] : 0;
    s[threadIdx.x] = v;
    __syncthreads();
    for (int off = 1; off < 512; off <<= 1) {
        int tv = (threadIdx.x >= off) ? s[threadIdx.x - off] : 0;
        __syncthreads();
        if (threadIdx.x >= off) s[threadIdx.x] += tv;
        __syncthreads();
    }
    if (i < nflat) data[i] = s[threadIdx.x] - v;
    if (threadIdx.x == 511) bsum[blockIdx.x] = s[511];
}

// single block, loops with running carry
__global__ void k_scan2(int* __restrict__ bsum, int nb) {
    __shared__ int s[512];
    __shared__ int carry;
    if (threadIdx.x == 0) carry = 0;
    __syncthreads();
    for (int base = 0; base < nb; base += 512) {
        int idx = base + threadIdx.x;
        int v = (idx < nb) ? bsum[idx] : 0;
        s[threadIdx.x] = v;
        __syncthreads();
        for (int off = 1; off < 512; off <<= 1) {
            int tv = (threadIdx.x >= off) ? s[threadIdx.x - off] : 0;
            __syncthreads();
            if (threadIdx.x >= off) s[threadIdx.x] += tv;
            __syncthreads();
        }
        if (idx < nb) bsum[idx] = s[threadIdx.x] - v + carry;
        __syncthreads();
        if (threadIdx.x == 0) carry += s[511];
        __syncthreads();
    }
}

// 1024 threads/block; scan3 folded into the lbase load.
__global__ void k_scatter(const int* __restrict__ ei, const float* __restrict__ ew,
                          const int* __restrict__ scanned, const int* __restrict__ bsum,
                          int2* __restrict__ ebuf, int E, int EPB, int NBK) {
    __shared__ int lbase[MAXBK];
    int b = blockIdx.x;
    for (int k = threadIdx.x; k < NBK; k += blockDim.x) {
        int idx = k * NBLKA + b;
        lbase[k] = scanned[idx] + bsum[idx >> 9];
    }
    __syncthreads();
    int e0 = b * EPB, e1 = min(E, e0 + EPB);
    for (int e = e0 + threadIdx.x; e < e1; e += blockDim.x) {
        int c = ei[E + e];
        int r = ei[e];
        int k = c >> BSH;
        int pos = atomicAdd(&lbase[k], 1);
        ebuf[pos] = make_int2(r | ((c & (BNODES - 1)) << 25), __float_as_int(ew[e]));
    }
}

// counting sort per bucket; writes compact 4B csr entries (unscaled w).
__global__ void k_sort(const int* __restrict__ scanned, const int* __restrict__ bsum,
                       const int2* __restrict__ ebuf,
                       int* __restrict__ row, float* __restrict__ dinv,
                       unsigned* __restrict__ csr4, int n, int E, int NBK) {
    __shared__ int lcnt[BNODES];
    __shared__ int lofs[BNODES];
    __shared__ float lw[BNODES];
    int k = blockIdx.x;
    if (threadIdx.x < BNODES) { lcnt[threadIdx.x] = 0; lw[threadIdx.x] = 1.0f; }
    __syncthreads();
    int idx0 = k * NBLKA;
    int bs = scanned[idx0] + bsum[idx0 >> 9];
    int be = E;
    if (k + 1 < NBK) {
        int idx1 = (k + 1) * NBLKA;
        be = scanned[idx1] + bsum[idx1 >> 9];
    }
    for (int s = bs + threadIdx.x; s < be; s += blockDim.x) {
        int2 ent = ebuf[s];
        int cl = ((unsigned)ent.x) >> 25;
        atomicAdd(&lcnt[cl], 1);
        atomicAdd(&lw[cl], __int_as_float(ent.y));
    }
    __syncthreads();
    int v = (threadIdx.x < BNODES) ? lcnt[threadIdx.x] : 0;
    if (threadIdx.x < BNODES) lofs[threadIdx.x] = v;
    __syncthreads();
    for (int off = 1; off < BNODES; off <<= 1) {
        int tv = 0;
        if (threadIdx.x < BNODES && threadIdx.x >= off) tv = lofs[threadIdx.x - off];
        __syncthreads();
        if (threadIdx.x < BNODES && threadIdx.x >= off) lofs[threadIdx.x] += tv;
        __syncthreads();
    }
    if (threadIdx.x < BNODES) {
        int excl = lofs[threadIdx.x] - v;
        lofs[threadIdx.x] = excl;
        int i = k * BNODES + threadIdx.x;
        if (i < n) {
            row[i] = bs + excl;
            dinv[i] = rsqrtf(lw[threadIdx.x]);
        }
    }
    if (k == NBK - 1 && threadIdx.x == 0) row[n] = E;
    __syncthreads();
    for (int s = bs + threadIdx.x; s < be; s += blockDim.x) {
        int2 ent = ebuf[s];
        int cl = ((unsigned)ent.x) >> 25;
        int pos = bs + atomicAdd(&lofs[cl], 1);
        csr4[pos] = enc_w(__int_as_float(ent.y)) | (unsigned)(ent.x & 0x1FFFF);
    }
}

// in-place rescale: w -> w * dinv[src]  (4B read + 4B write per edge)
__global__ void k_prep(unsigned* __restrict__ csr4, const float* __restrict__ dinv, int E) {
    int e = blockIdx.x * blockDim.x + threadIdx.x;
    if (e >= E) return;
    unsigned ent = csr4[e];
    unsigned src = ent & 0x1FFFFu;
    float wpre = dec_w(ent) * dinv[src];
    csr4[e] = enc_w(wpre) | src;
}

// pass1, 4 lanes/node, register-lean distributed tail.
__global__ void k_pass1(const int* __restrict__ row, const unsigned* __restrict__ csr4,
                        const float* __restrict__ dinv, const __half* __restrict__ xh,
                        const float* __restrict__ senc,
                        const float* __restrict__ W1, const float* __restrict__ b1,
                        const float* __restrict__ W2, __half* __restrict__ th, int n) {
    __shared__ float sW1[288];
    __shared__ float sb1[32];
    __shared__ float sW2[32 * 17];
    for (int j = threadIdx.x; j < 288; j += blockDim.x) sW1[j] = W1[j];
    for (int j = threadIdx.x; j < 512; j += blockDim.x) sW2[(j >> 4) * 17 + (j & 15)] = W2[j];
    if (threadIdx.x < 32) sb1[threadIdx.x] = b1[threadIdx.x];
    __syncthreads();
    int g = blockIdx.x * blockDim.x + threadIdx.x;
    int i = g >> 2;
    int quad = g & 3;
    if (i >= n) return;
    float di = dinv[i];
    float a[8];
    float sw;
    if (quad == 0) {
        const uint4* xp = reinterpret_cast<const uint4*>(xh + (size_t)i * 8);
        uint4 w = xp[0];
        const __half2* hh = reinterpret_cast<const __half2*>(&w);
        #pragma unroll
        for (int q = 0; q < 4; ++q) {
            float2 f = __half22float2(hh[q]);
            a[2 * q] = di * f.x; a[2 * q + 1] = di * f.y;
        }
        sw = di;
    } else {
        #pragma unroll
        for (int q = 0; q < 8; ++q) a[q] = 0.f;
        sw = 0.f;
    }
    int s0 = row[i], s1 = row[i + 1];
    for (int s = s0 + quad; s < s1; s += 4) {
        unsigned ent = csr4[s];
        float wpre = dec_w(ent);
        const uint4* xp = reinterpret_cast<const uint4*>(xh + (size_t)(ent & 0x1FFFFu) * 8);
        uint4 w = xp[0];
        const __half2* hh = reinterpret_cast<const __half2*>(&w);
        #pragma unroll
        for (int q = 0; q < 4; ++q) {
            float2 f = __half22float2(hh[q]);
            a[2 * q] += wpre * f.x; a[2 * q + 1] += wpre * f.y;
        }
        sw += wpre;
    }
    #pragma unroll
    for (int q = 0; q < 8; ++q) a[q] += __shfl_xor(a[q], 1);
    sw += __shfl_xor(sw, 1);
    #pragma unroll
    for (int q = 0; q < 8; ++q) a[q] += __shfl_xor(a[q], 2);
    sw += __shfl_xor(sw, 2);
    float a8 = di * sw * senc[0];
    float af[8];
    #pragma unroll
    for (int q = 0; q < 8; ++q) af[q] = di * a[q];
    float h[8];
    #pragma unroll
    for (int jj = 0; jj < 8; ++jj) {
        int j = quad * 8 + jj;
        float acc = sb1[j] + a8 * sW1[8 * 32 + j];
        #pragma unroll
        for (int f = 0; f < 8; ++f) acc += af[f] * sW1[f * 32 + j];
        h[jj] = acc > 0.f ? acc : 0.01f * acc;
    }
    float p[16];
    #pragma unroll
    for (int o = 0; o < 16; ++o) p[o] = 0.f;
    #pragma unroll
    for (int jj = 0; jj < 8; ++jj) {
        int j = quad * 8 + jj;
        #pragma unroll
        for (int o = 0; o < 16; ++o) p[o] += h[jj] * sW2[j * 17 + o];
    }
    #pragma unroll
    for (int o = 0; o < 16; ++o) p[o] += __shfl_xor(p[o], 1);
    #pragma unroll
    for (int o = 0; o < 16; ++o) p[o] += __shfl_xor(p[o], 2);
    int o0 = quad * 4;
    __half2 hv0 = __floats2half2_rn(p[o0 + 0], p[o0 + 1]);
    __half2 hv1 = __floats2half2_rn(p[o0 + 2], p[o0 + 3]);
    uint2 st;
    st.x = *reinterpret_cast<unsigned*>(&hv0);
    st.y = *reinterpret_cast<unsigned*>(&hv1);
    reinterpret_cast<uint2*>(th + (size_t)i * 16 + o0)[0] = st;
}

// pass2, 4 lanes/node
__global__ void k_pass2(const int* __restrict__ row, const unsigned* __restrict__ csr4,
                        const float* __restrict__ dinv, const __half* __restrict__ th,
                        const float* __restrict__ b2, const float* __restrict__ fw,
                        const float* __restrict__ fb, float* __restrict__ out, int n) {
    __shared__ float sb2[16];
    __shared__ float sfw[16];
    if (threadIdx.x < 16) { sb2[threadIdx.x] = b2[threadIdx.x]; sfw[threadIdx.x] = fw[threadIdx.x]; }
    __syncthreads();
    int g = blockIdx.x * blockDim.x + threadIdx.x;
    int i = g >> 2;
    int quad = g & 3;
    if (i >= n) return;
    float di = dinv[i];
    float acc[16];
    if (quad == 0) {
        const uint4* tp = reinterpret_cast<const uint4*>(th + (size_t)i * 16);
        uint4 w0 = tp[0], w1 = tp[1];
        const __half2* hh0 = reinterpret_cast<const __half2*>(&w0);
        const __half2* hh1 = reinterpret_cast<const __half2*>(&w1);
        #pragma unroll
        for (int q = 0; q < 4; ++q) {
            float2 f0 = __half22float2(hh0[q]);
            float2 f1 = __half22float2(hh1[q]);
            acc[2 * q + 0] = di * f0.x; acc[2 * q + 1] = di * f0.y;
            acc[8 + 2 * q + 0] = di * f1.x; acc[8 + 2 * q + 1] = di * f1.y;
        }
    } else {
        #pragma unroll
        for (int q = 0; q < 16; ++q) acc[q] = 0.f;
    }
    int s0 = row[i], s1 = row[i + 1];
    for (int s = s0 + quad; s < s1; s += 4) {
        unsigned ent = csr4[s];
        float wpre = dec_w(ent);
        const uint4* tp = reinterpret_cast<const uint4*>(th + (size_t)(ent & 0x1FFFFu) * 16);
        uint4 w0 = tp[0], w1 = tp[1];
        const __half2* hh0 = reinterpret_cast<const __half2*>(&w0);
        const __half2* hh1 = reinterpret_cast<const __half2*>(&w1);
        #pragma unroll
        for (int q = 0; q < 4; ++q) {
            float2 f0 = __half22float2(hh0[q]);
            float2 f1 = __half22float2(hh1[q]);
            acc[2 * q + 0] += wpre * f0.x; acc[2 * q + 1] += wpre * f0.y;
            acc[8 + 2 * q + 0] += wpre * f1.x; acc[8 + 2 * q + 1] += wpre * f1.y;
        }
    }
    #pragma unroll
    for (int q = 0; q < 16; ++q) acc[q] += __shfl_xor(acc[q], 1);
    #pragma unroll
    for (int q = 0; q < 16; ++q) acc[q] += __shfl_xor(acc[q], 2);
    if (quad) return;
    float o = fb[0];
    #pragma unroll
    for (int q = 0; q < 16; ++q) {
        float v = di * acc[q] + sb2[q];
        v = v > 0.f ? v : 0.01f * v;
        o += v * sfw[q];
    }
    out[i] = o;
}

extern "C" void kernel_launch(void* const* d_in, const int* in_sizes, int n_in,
                              void* d_out, int out_size, void* d_ws, size_t ws_size,
                              hipStream_t stream) {
    const float* x      = (const float*)d_in[0];
    const int*   ei     = (const int*)d_in[1];
    const float* ew     = (const float*)d_in[2];
    const float* sv     = (const float*)d_in[3];
    const float* sfc1w  = (const float*)d_in[4];
    const float* sfc1b  = (const float*)d_in[5];
    const float* sfc2w  = (const float*)d_in[6];
    const float* sfc2b  = (const float*)d_in[7];
    const float* conv1w = (const float*)d_in[8];
    const float* conv1b = (const float*)d_in[9];
    const float* conv2w = (const float*)d_in[10];
    const float* conv2b = (const float*)d_in[11];
    const float* fc1w   = (const float*)d_in[12];
    const float* fc1b   = (const float*)d_in[13];

    const int n = in_sizes[0] / 8;
    const int E = in_sizes[2];

    const int NBK   = (n + BNODES - 1) >> BSH;
    const int nflat = NBK * NBLKA;
    const int EPB   = (E + NBLKA - 1) / NBLKA;
    const int nb1   = (nflat + 511) / 512;

    size_t off = 0;
    auto alloc = [&](size_t words) { size_t o = off; off += (words + 3) & ~(size_t)3; return o; };
    float*    base = (float*)d_ws;
    float*    senc = base + alloc(4);
    float*    dinv = base + alloc(n);
    int*      rowp = (int*)(base + alloc(n + 1));
    int*      hist = (int*)(base + alloc(nflat));
    int*      bsum = (int*)(base + alloc(512));
    int2*     ebuf = (int2*)(base + alloc((size_t)2 * E));
    unsigned* csr4 = (unsigned*)(base + alloc(E));
    __half*   xh   = (__half*)(base + alloc((size_t)4 * n));
    __half*   th   = (__half*)(base + alloc((size_t)8 * n));

    const int BT = 256;
    const int gN = (n + BT - 1) / BT;
    const int gE = (E + BT - 1) / BT;
    const int g4 = ((size_t)4 * n + BT - 1) / BT;

    k_xh<<<gN + 1, BT, 0, stream>>>(x, xh, n, sv, sfc1w, sfc1b, sfc2w, sfc2b, senc);
    k_hist<<<NBLKA, 1024, 0, stream>>>(ei, hist, E, EPB, NBK);
    k_scan1<<<nb1, 512, 0, stream>>>(hist, bsum, nflat);
    k_scan2<<<1, 512, 0, stream>>>(bsum, nb1);
    k_scatter<<<NBLKA, 1024, 0, stream>>>(ei, ew, hist, bsum, ebuf, E, EPB, NBK);
    k_sort<<<NBK, 512, 0, stream>>>(hist, bsum, ebuf, rowp, dinv, csr4, n, E, NBK);
    k_prep<<<gE, BT, 0, stream>>>(csr4, dinv, E);
    k_pass1<<<g4, BT, 0, stream>>>(rowp, csr4, dinv, xh, senc,
                                   conv1w, conv1b, conv2w, th, n);
    k_pass2<<<g4, BT, 0, stream>>>(rowp, csr4, dinv, th,
                                   conv2b, fc1w, fc1b, (float*)d_out, n);
}

// Round 13
// 97.610 us; speedup vs baseline: 1.4162x; 1.0783x over previous
//
#include <hip/hip_runtime.h>
#include <hip/hip_fp16.h>

// ---------------------------------------------------------------------------
// EncodedGCN, round 12: 7 kernels.
//  - k_hist mega-kernel: blocks [0,NBLKA) histogram; next blocks convert x->
//    fp16 xh; last block computes the s-encoder scalar (independent work rides
//    the same launch).
//  - k_prep deleted: pass1 gathers dinv[src] (L2-resident 400KB), aggregates
//    with fp32 wpre, and writes the fp16-prescaled entry back to csr4 for
//    pass2. (-12.8MB r/w, -1 launch, pass2 unchanged.)
// Everything else = round 11 (105us).
// ---------------------------------------------------------------------------

#define NBLKA  256
#define BSH    7
#define BNODES 128
#define MAXBK  784

__device__ inline unsigned enc_w(float w) {
    return ((unsigned)__half_as_ushort(__float2half_rn(w)) & 0x7FFFu) << 17;
}
__device__ inline float dec_w(unsigned e) {
    return __half2float(__ushort_as_half((unsigned short)((e >> 17) & 0x7FFFu)));
}

// blocks [0,NBLKA): histogram; [NBLKA, NBLKA+gX): x->fp16; last: senc.
__global__ void k_hist(const int* __restrict__ ei, int* __restrict__ hist,
                       int E, int EPB, int NBK,
                       const float* __restrict__ x, __half* __restrict__ xh, int n,
                       const float* __restrict__ sv, const float* __restrict__ w1,
                       const float* __restrict__ b1, const float* __restrict__ w2,
                       const float* __restrict__ b2, float* __restrict__ senc) {
    if (blockIdx.x >= NBLKA) {
        if (blockIdx.x == gridDim.x - 1) {
            // s-encoder: 64x32 + relu + 32x1
            __shared__ float hid[32];
            int j = threadIdx.x;
            if (j < 32) {
                float acc = b1[j];
                #pragma unroll 8
                for (int k = 0; k < 64; ++k) acc += sv[k] * w1[k * 32 + j];
                hid[j] = acc > 0.f ? acc : 0.f;
            }
            __syncthreads();
            if (j == 0) {
                float acc = b2[0];
                #pragma unroll 8
                for (int k = 0; k < 32; ++k) acc += hid[k] * w2[k];
                senc[0] = acc;
            }
            return;
        }
        int i = (blockIdx.x - NBLKA) * blockDim.x + threadIdx.x;
        if (i >= n) return;
        const float4* xi = reinterpret_cast<const float4*>(x + (size_t)i * 8);
        float4 u = xi[0], v = xi[1];
        __half2 h0 = __floats2half2_rn(u.x, u.y);
        __half2 h1 = __floats2half2_rn(u.z, u.w);
        __half2 h2 = __floats2half2_rn(v.x, v.y);
        __half2 h3 = __floats2half2_rn(v.z, v.w);
        uint4 w;
        w.x = *reinterpret_cast<unsigned*>(&h0);
        w.y = *reinterpret_cast<unsigned*>(&h1);
        w.z = *reinterpret_cast<unsigned*>(&h2);
        w.w = *reinterpret_cast<unsigned*>(&h3);
        reinterpret_cast<uint4*>(xh + (size_t)i * 8)[0] = w;
        return;
    }
    __shared__ int lh[MAXBK];
    for (int k = threadIdx.x; k < NBK; k += blockDim.x) lh[k] = 0;
    __syncthreads();
    int b = blockIdx.x;
    int e0 = b * EPB, e1 = min(E, e0 + EPB);
    for (int e = e0 + threadIdx.x; e < e1; e += blockDim.x)
        atomicAdd(&lh[ei[E + e] >> BSH], 1);
    __syncthreads();
    for (int k = threadIdx.x; k < NBK; k += blockDim.x)
        hist[(size_t)k * NBLKA + b] = lh[k];
}

__global__ void k_scan1(int* __restrict__ data, int* __restrict__ bsum, int nflat) {
    __shared__ int s[512];
    int i = blockIdx.x * 512 + threadIdx.x;
    int v = (i < nflat) ? data[i] : 0;
    s[threadIdx.x] = v;
    __syncthreads();
    for (int off = 1; off < 512; off <<= 1) {
        int tv = (threadIdx.x >= off) ? s[threadIdx.x - off] : 0;
        __syncthreads();
        if (threadIdx.x >= off) s[threadIdx.x] += tv;
        __syncthreads();
    }
    if (i < nflat) data[i] = s[threadIdx.x] - v;
    if (threadIdx.x == 511) bsum[blockIdx.x] = s[511];
}

__global__ void k_scan2(int* __restrict__ bsum, int nb) {
    __shared__ int s[512];
    __shared__ int carry;
    if (threadIdx.x == 0) carry = 0;
    __syncthreads();
    for (int base = 0; base < nb; base += 512) {
        int idx = base + threadIdx.x;
        int v = (idx < nb) ? bsum[idx] : 0;
        s[threadIdx.x] = v;
        __syncthreads();
        for (int off = 1; off < 512; off <<= 1) {
            int tv = (threadIdx.x >= off) ? s[threadIdx.x - off] : 0;
            __syncthreads();
            if (threadIdx.x >= off) s[threadIdx.x] += tv;
            __syncthreads();
        }
        if (idx < nb) bsum[idx] = s[threadIdx.x] - v + carry;
        __syncthreads();
        if (threadIdx.x == 0) carry += s[511];
        __syncthreads();
    }
}

__global__ void k_scatter(const int* __restrict__ ei, const float* __restrict__ ew,
                          const int* __restrict__ scanned, const int* __restrict__ bsum,
                          int2* __restrict__ ebuf, int E, int EPB, int NBK) {
    __shared__ int lbase[MAXBK];
    int b = blockIdx.x;
    for (int k = threadIdx.x; k < NBK; k += blockDim.x) {
        int idx = k * NBLKA + b;
        lbase[k] = scanned[idx] + bsum[idx >> 9];
    }
    __syncthreads();
    int e0 = b * EPB, e1 = min(E, e0 + EPB);
    for (int e = e0 + threadIdx.x; e < e1; e += blockDim.x) {
        int c = ei[E + e];
        int r = ei[e];
        int k = c >> BSH;
        int pos = atomicAdd(&lbase[k], 1);
        ebuf[pos] = make_int2(r | ((c & (BNODES - 1)) << 25), __float_as_int(ew[e]));
    }
}

__global__ void k_sort(const int* __restrict__ scanned, const int* __restrict__ bsum,
                       const int2* __restrict__ ebuf,
                       int* __restrict__ row, float* __restrict__ dinv,
                       unsigned* __restrict__ csr4, int n, int E, int NBK) {
    __shared__ int lcnt[BNODES];
    __shared__ int lofs[BNODES];
    __shared__ float lw[BNODES];
    int k = blockIdx.x;
    if (threadIdx.x < BNODES) { lcnt[threadIdx.x] = 0; lw[threadIdx.x] = 1.0f; }
    __syncthreads();
    int idx0 = k * NBLKA;
    int bs = scanned[idx0] + bsum[idx0 >> 9];
    int be = E;
    if (k + 1 < NBK) {
        int idx1 = (k + 1) * NBLKA;
        be = scanned[idx1] + bsum[idx1 >> 9];
    }
    for (int s = bs + threadIdx.x; s < be; s += blockDim.x) {
        int2 ent = ebuf[s];
        int cl = ((unsigned)ent.x) >> 25;
        atomicAdd(&lcnt[cl], 1);
        atomicAdd(&lw[cl], __int_as_float(ent.y));
    }
    __syncthreads();
    int v = (threadIdx.x < BNODES) ? lcnt[threadIdx.x] : 0;
    if (threadIdx.x < BNODES) lofs[threadIdx.x] = v;
    __syncthreads();
    for (int off = 1; off < BNODES; off <<= 1) {
        int tv = 0;
        if (threadIdx.x < BNODES && threadIdx.x >= off) tv = lofs[threadIdx.x - off];
        __syncthreads();
        if (threadIdx.x < BNODES && threadIdx.x >= off) lofs[threadIdx.x] += tv;
        __syncthreads();
    }
    if (threadIdx.x < BNODES) {
        int excl = lofs[threadIdx.x] - v;
        lofs[threadIdx.x] = excl;
        int i = k * BNODES + threadIdx.x;
        if (i < n) {
            row[i] = bs + excl;
            dinv[i] = rsqrtf(lw[threadIdx.x]);
        }
    }
    if (k == NBK - 1 && threadIdx.x == 0) row[n] = E;
    __syncthreads();
    for (int s = bs + threadIdx.x; s < be; s += blockDim.x) {
        int2 ent = ebuf[s];
        int cl = ((unsigned)ent.x) >> 25;
        int pos = bs + atomicAdd(&lofs[cl], 1);
        csr4[pos] = enc_w(__int_as_float(ent.y)) | (unsigned)(ent.x & 0x1FFFF);
    }
}

// pass1, 4 lanes/node: gathers dinv[src], aggregates with fp32 wpre, writes
// prescaled fp16 entry back to csr4 for pass2.
__global__ void k_pass1(const int* __restrict__ row, unsigned* __restrict__ csr4,
                        const float* __restrict__ dinv, const __half* __restrict__ xh,
                        const float* __restrict__ senc,
                        const float* __restrict__ W1, const float* __restrict__ b1,
                        const float* __restrict__ W2, __half* __restrict__ th, int n) {
    __shared__ float sW1[288];
    __shared__ float sb1[32];
    __shared__ float sW2[32 * 17];
    for (int j = threadIdx.x; j < 288; j += blockDim.x) sW1[j] = W1[j];
    for (int j = threadIdx.x; j < 512; j += blockDim.x) sW2[(j >> 4) * 17 + (j & 15)] = W2[j];
    if (threadIdx.x < 32) sb1[threadIdx.x] = b1[threadIdx.x];
    __syncthreads();
    int g = blockIdx.x * blockDim.x + threadIdx.x;
    int i = g >> 2;
    int quad = g & 3;
    if (i >= n) return;
    float di = dinv[i];
    float a[8];
    float sw;
    if (quad == 0) {
        const uint4* xp = reinterpret_cast<const uint4*>(xh + (size_t)i * 8);
        uint4 w = xp[0];
        const __half2* hh = reinterpret_cast<const __half2*>(&w);
        #pragma unroll
        for (int q = 0; q < 4; ++q) {
            float2 f = __half22float2(hh[q]);
            a[2 * q] = di * f.x; a[2 * q + 1] = di * f.y;
        }
        sw = di;
    } else {
        #pragma unroll
        for (int q = 0; q < 8; ++q) a[q] = 0.f;
        sw = 0.f;
    }
    int s0 = row[i], s1 = row[i + 1];
    for (int s = s0 + quad; s < s1; s += 4) {
        unsigned ent = csr4[s];
        unsigned src = ent & 0x1FFFFu;
        float wpre = dec_w(ent) * dinv[src];
        csr4[s] = enc_w(wpre) | src;   // prescaled for pass2
        const uint4* xp = reinterpret_cast<const uint4*>(xh + (size_t)src * 8);
        uint4 w = xp[0];
        const __half2* hh = reinterpret_cast<const __half2*>(&w);
        #pragma unroll
        for (int q = 0; q < 4; ++q) {
            float2 f = __half22float2(hh[q]);
            a[2 * q] += wpre * f.x; a[2 * q + 1] += wpre * f.y;
        }
        sw += wpre;
    }
    #pragma unroll
    for (int q = 0; q < 8; ++q) a[q] += __shfl_xor(a[q], 1);
    sw += __shfl_xor(sw, 1);
    #pragma unroll
    for (int q = 0; q < 8; ++q) a[q] += __shfl_xor(a[q], 2);
    sw += __shfl_xor(sw, 2);
    float a8 = di * sw * senc[0];
    float af[8];
    #pragma unroll
    for (int q = 0; q < 8; ++q) af[q] = di * a[q];
    float h[8];
    #pragma unroll
    for (int jj = 0; jj < 8; ++jj) {
        int j = quad * 8 + jj;
        float acc = sb1[j] + a8 * sW1[8 * 32 + j];
        #pragma unroll
        for (int f = 0; f < 8; ++f) acc += af[f] * sW1[f * 32 + j];
        h[jj] = acc > 0.f ? acc : 0.01f * acc;
    }
    float p[16];
    #pragma unroll
    for (int o = 0; o < 16; ++o) p[o] = 0.f;
    #pragma unroll
    for (int jj = 0; jj < 8; ++jj) {
        int j = quad * 8 + jj;
        #pragma unroll
        for (int o = 0; o < 16; ++o) p[o] += h[jj] * sW2[j * 17 + o];
    }
    #pragma unroll
    for (int o = 0; o < 16; ++o) p[o] += __shfl_xor(p[o], 1);
    #pragma unroll
    for (int o = 0; o < 16; ++o) p[o] += __shfl_xor(p[o], 2);
    int o0 = quad * 4;
    __half2 hv0 = __floats2half2_rn(p[o0 + 0], p[o0 + 1]);
    __half2 hv1 = __floats2half2_rn(p[o0 + 2], p[o0 + 3]);
    uint2 st;
    st.x = *reinterpret_cast<unsigned*>(&hv0);
    st.y = *reinterpret_cast<unsigned*>(&hv1);
    reinterpret_cast<uint2*>(th + (size_t)i * 16 + o0)[0] = st;
}

// pass2, 4 lanes/node (prescaled csr4)
__global__ void k_pass2(const int* __restrict__ row, const unsigned* __restrict__ csr4,
                        const float* __restrict__ dinv, const __half* __restrict__ th,
                        const float* __restrict__ b2, const float* __restrict__ fw,
                        const float* __restrict__ fb, float* __restrict__ out, int n) {
    __shared__ float sb2[16];
    __shared__ float sfw[16];
    if (threadIdx.x < 16) { sb2[threadIdx.x] = b2[threadIdx.x]; sfw[threadIdx.x] = fw[threadIdx.x]; }
    __syncthreads();
    int g = blockIdx.x * blockDim.x + threadIdx.x;
    int i = g >> 2;
    int quad = g & 3;
    if (i >= n) return;
    float di = dinv[i];
    float acc[16];
    if (quad == 0) {
        const uint4* tp = reinterpret_cast<const uint4*>(th + (size_t)i * 16);
        uint4 w0 = tp[0], w1 = tp[1];
        const __half2* hh0 = reinterpret_cast<const __half2*>(&w0);
        const __half2* hh1 = reinterpret_cast<const __half2*>(&w1);
        #pragma unroll
        for (int q = 0; q < 4; ++q) {
            float2 f0 = __half22float2(hh0[q]);
            float2 f1 = __half22float2(hh1[q]);
            acc[2 * q + 0] = di * f0.x; acc[2 * q + 1] = di * f0.y;
            acc[8 + 2 * q + 0] = di * f1.x; acc[8 + 2 * q + 1] = di * f1.y;
        }
    } else {
        #pragma unroll
        for (int q = 0; q < 16; ++q) acc[q] = 0.f;
    }
    int s0 = row[i], s1 = row[i + 1];
    for (int s = s0 + quad; s < s1; s += 4) {
        unsigned ent = csr4[s];
        float wpre = dec_w(ent);
        const uint4* tp = reinterpret_cast<const uint4*>(th + (size_t)(ent & 0x1FFFFu) * 16);
        uint4 w0 = tp[0], w1 = tp[1];
        const __half2* hh0 = reinterpret_cast<const __half2*>(&w0);
        const __half2* hh1 = reinterpret_cast<const __half2*>(&w1);
        #pragma unroll
        for (int q = 0; q < 4; ++q) {
            float2 f0 = __half22float2(hh0[q]);
            float2 f1 = __half22float2(hh1[q]);
            acc[2 * q + 0] += wpre * f0.x; acc[2 * q + 1] += wpre * f0.y;
            acc[8 + 2 * q + 0] += wpre * f1.x; acc[8 + 2 * q + 1] += wpre * f1.y;
        }
    }
    #pragma unroll
    for (int q = 0; q < 16; ++q) acc[q] += __shfl_xor(acc[q], 1);
    #pragma unroll
    for (int q = 0; q < 16; ++q) acc[q] += __shfl_xor(acc[q], 2);
    if (quad) return;
    float o = fb[0];
    #pragma unroll
    for (int q = 0; q < 16; ++q) {
        float v = di * acc[q] + sb2[q];
        v = v > 0.f ? v : 0.01f * v;
        o += v * sfw[q];
    }
    out[i] = o;
}

extern "C" void kernel_launch(void* const* d_in, const int* in_sizes, int n_in,
                              void* d_out, int out_size, void* d_ws, size_t ws_size,
                              hipStream_t stream) {
    const float* x      = (const float*)d_in[0];
    const int*   ei     = (const int*)d_in[1];
    const float* ew     = (const float*)d_in[2];
    const float* sv     = (const float*)d_in[3];
    const float* sfc1w  = (const float*)d_in[4];
    const float* sfc1b  = (const float*)d_in[5];
    const float* sfc2w  = (const float*)d_in[6];
    const float* sfc2b  = (const float*)d_in[7];
    const float* conv1w = (const float*)d_in[8];
    const float* conv1b = (const float*)d_in[9];
    const float* conv2w = (const float*)d_in[10];
    const float* conv2b = (const float*)d_in[11];
    const float* fc1w   = (const float*)d_in[12];
    const float* fc1b   = (const float*)d_in[13];

    const int n = in_sizes[0] / 8;
    const int E = in_sizes[2];

    const int NBK   = (n + BNODES - 1) >> BSH;
    const int nflat = NBK * NBLKA;
    const int EPB   = (E + NBLKA - 1) / NBLKA;
    const int nb1   = (nflat + 511) / 512;
    const int gX    = (n + 1023) / 1024;   // xh rider blocks (1024 thr)

    size_t off = 0;
    auto alloc = [&](size_t words) { size_t o = off; off += (words + 3) & ~(size_t)3; return o; };
    float*    base = (float*)d_ws;
    float*    senc = base + alloc(4);
    float*    dinv = base + alloc(n);
    int*      rowp = (int*)(base + alloc(n + 1));
    int*      hist = (int*)(base + alloc(nflat));
    int*      bsum = (int*)(base + alloc(512));
    int2*     ebuf = (int2*)(base + alloc((size_t)2 * E));
    unsigned* csr4 = (unsigned*)(base + alloc(E));
    __half*   xh   = (__half*)(base + alloc((size_t)4 * n));
    __half*   th   = (__half*)(base + alloc((size_t)8 * n));

    const int BT = 256;
    const int g4 = ((size_t)4 * n + BT - 1) / BT;

    k_hist<<<NBLKA + gX + 1, 1024, 0, stream>>>(ei, hist, E, EPB, NBK,
                                                x, xh, n,
                                                sv, sfc1w, sfc1b, sfc2w, sfc2b, senc);
    k_scan1<<<nb1, 512, 0, stream>>>(hist, bsum, nflat);
    k_scan2<<<1, 512, 0, stream>>>(bsum, nb1);
    k_scatter<<<NBLKA, 1024, 0, stream>>>(ei, ew, hist, bsum, ebuf, E, EPB, NBK);
    k_sort<<<NBK, 512, 0, stream>>>(hist, bsum, ebuf, rowp, dinv, csr4, n, E, NBK);
    k_pass1<<<g4, BT, 0, stream>>>(rowp, csr4, dinv, xh, senc,
                                   conv1w, conv1b, conv2w, th, n);
    k_pass2<<<g4, BT, 0, stream>>>(rowp, csr4, dinv, th,
                                   conv2b, fc1w, fc1b, (float*)d_out, n);
}